// Round 9
// baseline (652.191 us; speedup 1.0000x reference)
//
#include <hip/hip_runtime.h>
#include <math.h>

#define PP 196608
#define NK 8

#define O_SIGALL 589824
#define O_RGB    786432
#define O_SIG    5505024

typedef __attribute__((ext_vector_type(8))) short short8;
typedef __attribute__((ext_vector_type(4))) float f32x4;

// ---- workspace byte offsets ----
#define OW_B0 0
#define OW_B1 8192
#define OW_B2 16384
#define OW_A0 24576
#define OW_A1 40960
#define OW_A2 49152
#define OW_L  57344
#define OW_V  65536
#define OW_C0 71680
#define OW_C1 72704
#define OB_B0 73728
#define OB_A0 75776
#define OB_B1 77824
#define OB_B2 78080
#define OB_A1 78336
#define OB_A2 78592
#define OB_L  78848
#define OB_V  79104
#define OB_C0 79232
#define OB_C1 79296
#define OB_W32B0 79360
#define OB_W32A0 79616

__device__ __forceinline__ short bfr(float f) {
    unsigned u = __builtin_bit_cast(unsigned, f);
    unsigned r = (u + 0x7FFFu + ((u >> 16) & 1u)) >> 16;
    return (short)r;
}

__device__ __forceinline__ int tau(int p) {
    return 16 * ((p >> 2) & 1) + 4 * (p >> 3) + (p & 3);
}

__device__ __forceinline__ float pe_elem(int j, float c0, float c1, float c2, int jmax) {
    int r = j - 3;
    int rf = r < 0 ? 0 : r;
    int f = rf / 6;
    int t = rf - 6 * f;
    int comp = (j < 3) ? j : (t >= 3 ? t - 3 : t);
    float c = (comp == 0) ? c0 : ((comp == 1) ? c1 : c2);
    float x = c * (float)(1 << f);
    float val = (t < 3) ? sinf(x) : cosf(x);
    if (j < 3) val = c;
    return (j < jmax) ? val : 0.f;
}

__device__ __forceinline__ float softplus_(float d) {
    return fmaxf(d, 0.f) + log1pf(expf(-fabsf(d)));
}

#define MFMA(a, b, c) __builtin_amdgcn_mfma_f32_16x16x32_bf16(a, b, c, 0, 0, 0)

// ================= prep kernel (unchanged from R8) =================
__global__ void prep_kernel(
    const float* __restrict__ slots,
    const float* __restrict__ Wb0, const float* __restrict__ bb0,
    const float* __restrict__ Wb1, const float* __restrict__ bb1,
    const float* __restrict__ Wb2, const float* __restrict__ bb2,
    const float* __restrict__ Wa0, const float* __restrict__ ba0,
    const float* __restrict__ Wa1, const float* __restrict__ ba1,
    const float* __restrict__ Wa2, const float* __restrict__ ba2,
    const float* __restrict__ Wl,  const float* __restrict__ bl,
    const float* __restrict__ Wv,  const float* __restrict__ bv,
    const float* __restrict__ Wc0, const float* __restrict__ bc0,
    const float* __restrict__ Wc1, const float* __restrict__ bc1,
    char* __restrict__ ws)
{
    short* wsS = (short*)ws;
    float* wsF = (float*)ws;
    const int tid = threadIdx.x;

    for (int idx = tid; idx < 64 * 64; idx += 256) {
        int j = idx >> 6, C = idx & 63;
        int lc = (C & ~31) + tau(C & 31);
        wsS[OW_B0 / 2 + idx] = bfr(lc < 33 ? Wb0[j * 97 + lc] : 0.f);
    }
    for (int idx = tid; idx < 64 * 64; idx += 256) {
        int j = idx >> 6, C = idx & 63;
        int lc = (C & ~31) + tau(C & 31);
        wsS[OW_B1 / 2 + idx] = bfr(Wb1[j * 64 + lc]);
        wsS[OW_B2 / 2 + idx] = bfr(Wb2[j * 64 + lc]);
        wsS[OW_A1 / 2 + idx] = bfr(Wa1[j * 64 + lc]);
        wsS[OW_A2 / 2 + idx] = bfr(Wa2[j * 64 + lc]);
        wsS[OW_L  / 2 + idx] = bfr(Wl [j * 64 + lc]);
    }
    for (int idx = tid; idx < 64 * 128; idx += 256) {
        int j = idx >> 7, C = idx & 127;
        int lc = (C & ~31) + tau(C & 31);
        float v = 0.f;
        if (lc < 33) v = Wa0[j * 161 + lc];
        else if (lc >= 64) v = Wa0[j * 161 + 33 + lc];
        wsS[OW_A0 / 2 + idx] = bfr(v);
    }
    for (int idx = tid; idx < 32 * 96; idx += 256) {
        int j = idx / 96, C = idx % 96;
        int lc = (C & ~31) + tau(C & 31);
        wsS[OW_V / 2 + idx] = bfr(lc < 85 ? Wv[j * 85 + lc] : 0.f);
    }
    for (int idx = tid; idx < 16 * 32; idx += 256) {
        int j = idx >> 5, C = idx & 31;
        wsS[OW_C0 / 2 + idx] = bfr(Wc0[j * 32 + tau(C)]);
    }
    for (int idx = tid; idx < 16 * 32; idx += 256) {
        int j = idx >> 5, C = idx & 31;
        int lc = tau(C);
        wsS[OW_C1 / 2 + idx] = bfr((j < 3 && lc < 16) ? Wc1[j * 16 + lc] : 0.f);
    }
    for (int idx = tid; idx < 512; idx += 256) {
        int k = idx >> 6, j = idx & 63;
        const float* sl = slots + k * 64;
        float a = bb0[j];
        const float* w0 = Wb0 + j * 97 + 33;
        for (int i = 0; i < 64; ++i) a = fmaf(w0[i], sl[i], a);
        wsF[OB_B0 / 4 + idx] = a;
        float b = ba0[j];
        const float* w1 = Wa0 + j * 161 + 33;
        for (int i = 0; i < 64; ++i) b = fmaf(w1[i], sl[i], b);
        wsF[OB_A0 / 4 + idx] = b;
    }
    for (int idx = tid; idx < 64; idx += 256) {
        wsF[OB_B1 / 4 + idx] = bb1[idx];
        wsF[OB_B2 / 4 + idx] = bb2[idx];
        wsF[OB_A1 / 4 + idx] = ba1[idx];
        wsF[OB_A2 / 4 + idx] = ba2[idx];
        wsF[OB_L  / 4 + idx] = bl[idx];
        wsF[OB_W32B0 / 4 + idx] = Wb0[idx * 97 + 32];
        wsF[OB_W32A0 / 4 + idx] = Wa0[idx * 161 + 32];
        if (idx < 32) wsF[OB_V / 4 + idx] = bv[idx];
        if (idx < 16) wsF[OB_C0 / 4 + idx] = bc0[idx];
        if (idx < 16) wsF[OB_C1 / 4 + idx] = (idx < 3) ? bc1[idx] : 0.f;
    }
}

// ---- alloca-free building blocks (macros; named variables only) ----
#define LDA_(OFF, t, s, KP) (*(const short8*)(wsS + (OFF) / 2 + (16 * (t) + l15) * (KP) + 32 * (s) + g8))
#define LDBIAS(OFF, t) (*(const f32x4*)(wsF + (OFF) / 4 + 16 * (t) + g4))
#define LDBP(PTR, t) (*(const f32x4*)((PTR) + 16 * (t) + g4))

#define PACKP(cA, cB, dst) { short8 f_; \
  f_[0]=bfr(fmaxf((cA)[0],0.f)); f_[1]=bfr(fmaxf((cA)[1],0.f)); f_[2]=bfr(fmaxf((cA)[2],0.f)); f_[3]=bfr(fmaxf((cA)[3],0.f)); \
  f_[4]=bfr(fmaxf((cB)[0],0.f)); f_[5]=bfr(fmaxf((cB)[1],0.f)); f_[6]=bfr(fmaxf((cB)[2],0.f)); f_[7]=bfr(fmaxf((cB)[3],0.f)); \
  dst = f_; }

#define PACKN(cA, cB, dst) { short8 f_; \
  f_[0]=bfr((cA)[0]); f_[1]=bfr((cA)[1]); f_[2]=bfr((cA)[2]); f_[3]=bfr((cA)[3]); \
  f_[4]=bfr((cB)[0]); f_[5]=bfr((cB)[1]); f_[6]=bfr((cB)[2]); f_[7]=bfr((cB)[3]); \
  dst = f_; }

#define ADD32(c, wv) { (c)[0]=fmaf((wv)[0],cosv,(c)[0]); (c)[1]=fmaf((wv)[1],cosv,(c)[1]); \
                       (c)[2]=fmaf((wv)[2],cosv,(c)[2]); (c)[3]=fmaf((wv)[3],cosv,(c)[3]); }

// standard 64x64 layer for both slots; acts in p00,p01,p10,p11
#define LAYER64(WOFF, BOFF, PK) { \
  short8 A00=LDA_(WOFF,0,0,64), A10=LDA_(WOFF,1,0,64), A20=LDA_(WOFF,2,0,64), A30=LDA_(WOFF,3,0,64); \
  short8 A01=LDA_(WOFF,0,1,64), A11=LDA_(WOFF,1,1,64), A21=LDA_(WOFF,2,1,64), A31=LDA_(WOFF,3,1,64); \
  f32x4 c0=LDBIAS(BOFF,0), c1=LDBIAS(BOFF,1), c2=LDBIAS(BOFF,2), c3=LDBIAS(BOFF,3); \
  f32x4 d0=c0, d1=c1, d2=c2, d3=c3; \
  c0=MFMA(A00,p00,c0); c1=MFMA(A10,p00,c1); c2=MFMA(A20,p00,c2); c3=MFMA(A30,p00,c3); \
  c0=MFMA(A01,p01,c0); c1=MFMA(A11,p01,c1); c2=MFMA(A21,p01,c2); c3=MFMA(A31,p01,c3); \
  d0=MFMA(A00,p10,d0); d1=MFMA(A10,p10,d1); d2=MFMA(A20,p10,d2); d3=MFMA(A30,p10,d3); \
  d0=MFMA(A01,p11,d0); d1=MFMA(A11,p11,d1); d2=MFMA(A21,p11,d2); d3=MFMA(A31,p11,d3); \
  PK(c0,c1,p00); PK(c2,c3,p01); PK(d0,d1,p10); PK(d2,d3,p11); }

#define TAIL(PA, PB, WSEL, SLOT) { \
  f32x4 cv0 = LDBIAS(OB_V, 0), cv1 = LDBIAS(OB_V, 1); \
  cv0 = MFMA(AV00, PA, cv0); cv1 = MFMA(AV10, PA, cv1); \
  cv0 = MFMA(AV01, PB, cv0); cv1 = MFMA(AV11, PB, cv1); \
  cv0 = MFMA(AV02, vembB, cv0); cv1 = MFMA(AV12, vembB, cv1); \
  short8 vB_; \
  vB_[0]=bfr(fmaxf(cv0[0],0.f)); vB_[1]=bfr(fmaxf(cv0[1],0.f)); vB_[2]=bfr(fmaxf(cv0[2],0.f)); vB_[3]=bfr(fmaxf(cv0[3],0.f)); \
  vB_[4]=bfr(fmaxf(cv1[0],0.f)); vB_[5]=bfr(fmaxf(cv1[1],0.f)); vB_[6]=bfr(fmaxf(cv1[2],0.f)); vB_[7]=bfr(fmaxf(cv1[3],0.f)); \
  f32x4 cc = LDBIAS(OB_C0, 0); \
  cc = MFMA(AC0, vB_, cc); \
  short8 cB_; \
  cB_[0]=bfr(fmaxf(cc[0],0.f)); cB_[1]=bfr(fmaxf(cc[1],0.f)); cB_[2]=bfr(fmaxf(cc[2],0.f)); cB_[3]=bfr(fmaxf(cc[3],0.f)); \
  cB_[4]=0; cB_[5]=0; cB_[6]=0; cB_[7]=0; \
  f32x4 cf = LDBIAS(OB_C1, 0); \
  cf = MFMA(AC1, cB_, cf); \
  float r0_ = (tanhf(cf[0]) + 1.f) * 0.5f; \
  float r1_ = (tanhf(cf[1]) + 1.f) * 0.5f; \
  float r2_ = (tanhf(cf[2]) + 1.f) * 0.5f; \
  rgbA0 = fmaf(WSEL, r0_, rgbA0); rgbA1 = fmaf(WSEL, r1_, rgbA1); rgbA2 = fmaf(WSEL, r2_, rgbA2); \
  if (l < 16) { int base_ = O_RGB + ((SLOT) * PP + p) * 3; \
    out[base_ + 0] = r0_; out[base_ + 1] = r1_; out[base_ + 2] = r2_; } }

// ================= main kernel =================
__global__ __launch_bounds__(256, 2) void decoder_kernel(
    const float* __restrict__ coor,
    const float* __restrict__ view,
    const float* __restrict__ dens,
    const float* __restrict__ act_shift,
    const int*   __restrict__ ray_id,
    const char*  __restrict__ ws,
    float* __restrict__ out)
{
    const short* wsS = (const short*)ws;
    const float* wsF = (const float*)ws;
    const int tid = threadIdx.x;
    const int l   = tid & 63;
    const int l15 = l & 15;
    const int g   = (l >> 4) & 3;
    const int g8  = g * 8;
    const int g4  = g * 4;
    const int p   = blockIdx.x * 64 + (tid >> 6) * 16 + l15;

    // ---- pos-emb fragment (cols 0..31) + col-32 scalar ----
    short8 embB0;
    float cosv;
    {
        float c0 = coor[p * 3 + 0], c1 = coor[p * 3 + 1], c2 = coor[p * 3 + 2];
        #pragma unroll
        for (int i = 0; i < 8; ++i) {
            int j = ((i >> 2) * 16) + 4 * g + (i & 3);
            embB0[i] = bfr(pe_elem(j, c0, c1, c2, 33));
        }
        cosv = cosf(c2 * 16.f);
    }
    // ---- view embedding fragment (jmax=21) ----
    short8 vembB;
    {
        int rid = ray_id[p];
        float v0 = view[rid * 3 + 0], v1 = view[rid * 3 + 1], v2 = view[rid * 3 + 2];
        #pragma unroll
        for (int i = 0; i < 8; ++i) {
            int j = ((i >> 2) * 16) + 4 * g + (i & 3);
            vembB[i] = bfr(pe_elem(j, v0, v1, v2, 21));
        }
    }

    // ---- masks / sigma: all named scalars ----
    float shift = act_shift[0];
    float sp0, sp1, sp2, sp3, sp4, sp5, sp6, sp7;
#define SPC(i) { float d_ = dens[(i) * PP + p] + shift; sp##i = softplus_(d_); \
                 if (l < 16) out[O_SIG + (i) * PP + p] = sp##i; }
    SPC(0) SPC(1) SPC(2) SPC(3) SPC(4) SPC(5) SPC(6) SPC(7)
#undef SPC
    float msum = sp0 + sp1 + sp2 + sp3 + sp4 + sp5 + sp6 + sp7;
    float inv = 1.f / (msum + 1e-5f);
    float mk2 = sp0*sp0 + sp1*sp1 + sp2*sp2 + sp3*sp3 + sp4*sp4 + sp5*sp5 + sp6*sp6 + sp7*sp7;
    if (l < 16) out[O_SIGALL + p] = mk2 * inv;
    float w0 = sp0 * inv, w1 = sp1 * inv, w2 = sp2 * inv, w3 = sp3 * inv;
    float w4 = sp4 * inv, w5 = sp5 * inv, w6 = sp6 * inv, w7 = sp7 * inv;

    float rgbA0 = 0.f, rgbA1 = 0.f, rgbA2 = 0.f;
    short8 p00, p01, p10, p11;   // activation frags: slot{0,1} x slice{0,1}

    #pragma unroll 1
    for (int kq = 0; kq < 4; ++kq) {
        const float* BB0 = wsF + OB_B0 / 4 + kq * 128;
        const float* BA0 = wsF + OB_A0 / 4 + kq * 128;

        { // b0: emb(MFMA, cols 0..31) + col32(VALU) -> 64
            short8 A0 = LDA_(OW_B0, 0, 0, 64), A1 = LDA_(OW_B0, 1, 0, 64);
            short8 A2 = LDA_(OW_B0, 2, 0, 64), A3 = LDA_(OW_B0, 3, 0, 64);
            f32x4 wv0 = LDBIAS(OB_W32B0, 0), wv1 = LDBIAS(OB_W32B0, 1);
            f32x4 wv2 = LDBIAS(OB_W32B0, 2), wv3 = LDBIAS(OB_W32B0, 3);
            f32x4 c0 = LDBP(BB0, 0), c1 = LDBP(BB0, 1), c2 = LDBP(BB0, 2), c3 = LDBP(BB0, 3);
            c0 = MFMA(A0, embB0, c0); c1 = MFMA(A1, embB0, c1);
            c2 = MFMA(A2, embB0, c2); c3 = MFMA(A3, embB0, c3);
            ADD32(c0, wv0) ADD32(c1, wv1) ADD32(c2, wv2) ADD32(c3, wv3)
            PACKP(c0, c1, p00); PACKP(c2, c3, p01);
            f32x4 d0 = LDBP(BB0 + 64, 0), d1 = LDBP(BB0 + 64, 1), d2 = LDBP(BB0 + 64, 2), d3 = LDBP(BB0 + 64, 3);
            d0 = MFMA(A0, embB0, d0); d1 = MFMA(A1, embB0, d1);
            d2 = MFMA(A2, embB0, d2); d3 = MFMA(A3, embB0, d3);
            ADD32(d0, wv0) ADD32(d1, wv1) ADD32(d2, wv2) ADD32(d3, wv3)
            PACKP(d0, d1, p10); PACKP(d2, d3, p11);
        }
        LAYER64(OW_B1, OB_B1, PACKP)
        LAYER64(OW_B2, OB_B2, PACKP)
        { // a0: emb(MFMA) + col32(VALU) + skip(MFMA x2) -> 64
            short8 E0 = LDA_(OW_A0, 0, 0, 128), E1 = LDA_(OW_A0, 1, 0, 128);
            short8 E2 = LDA_(OW_A0, 2, 0, 128), E3 = LDA_(OW_A0, 3, 0, 128);
            short8 S00 = LDA_(OW_A0, 0, 2, 128), S10 = LDA_(OW_A0, 1, 2, 128);
            short8 S20 = LDA_(OW_A0, 2, 2, 128), S30 = LDA_(OW_A0, 3, 2, 128);
            short8 S01 = LDA_(OW_A0, 0, 3, 128), S11 = LDA_(OW_A0, 1, 3, 128);
            short8 S21 = LDA_(OW_A0, 2, 3, 128), S31 = LDA_(OW_A0, 3, 3, 128);
            f32x4 wv0 = LDBIAS(OB_W32A0, 0), wv1 = LDBIAS(OB_W32A0, 1);
            f32x4 wv2 = LDBIAS(OB_W32A0, 2), wv3 = LDBIAS(OB_W32A0, 3);
            f32x4 c0 = LDBP(BA0, 0), c1 = LDBP(BA0, 1), c2 = LDBP(BA0, 2), c3 = LDBP(BA0, 3);
            c0 = MFMA(E0, embB0, c0); c1 = MFMA(E1, embB0, c1);
            c2 = MFMA(E2, embB0, c2); c3 = MFMA(E3, embB0, c3);
            c0 = MFMA(S00, p00, c0); c1 = MFMA(S10, p00, c1);
            c2 = MFMA(S20, p00, c2); c3 = MFMA(S30, p00, c3);
            c0 = MFMA(S01, p01, c0); c1 = MFMA(S11, p01, c1);
            c2 = MFMA(S21, p01, c2); c3 = MFMA(S31, p01, c3);
            ADD32(c0, wv0) ADD32(c1, wv1) ADD32(c2, wv2) ADD32(c3, wv3)
            f32x4 d0 = LDBP(BA0 + 64, 0), d1 = LDBP(BA0 + 64, 1), d2 = LDBP(BA0 + 64, 2), d3 = LDBP(BA0 + 64, 3);
            d0 = MFMA(E0, embB0, d0); d1 = MFMA(E1, embB0, d1);
            d2 = MFMA(E2, embB0, d2); d3 = MFMA(E3, embB0, d3);
            d0 = MFMA(S00, p10, d0); d1 = MFMA(S10, p10, d1);
            d2 = MFMA(S20, p10, d2); d3 = MFMA(S30, p10, d3);
            d0 = MFMA(S01, p11, d0); d1 = MFMA(S11, p11, d1);
            d2 = MFMA(S21, p11, d2); d3 = MFMA(S31, p11, d3);
            ADD32(d0, wv0) ADD32(d1, wv1) ADD32(d2, wv2) ADD32(d3, wv3)
            PACKP(c0, c1, p00); PACKP(c2, c3, p01);
            PACKP(d0, d1, p10); PACKP(d2, d3, p11);
        }
        LAYER64(OW_A1, OB_A1, PACKP)
        LAYER64(OW_A2, OB_A2, PACKP)
        LAYER64(OW_L,  OB_L,  PACKN)
        { // tail for both slots
            short8 AV00 = LDA_(OW_V, 0, 0, 96), AV10 = LDA_(OW_V, 1, 0, 96);
            short8 AV01 = LDA_(OW_V, 0, 1, 96), AV11 = LDA_(OW_V, 1, 1, 96);
            short8 AV02 = LDA_(OW_V, 0, 2, 96), AV12 = LDA_(OW_V, 1, 2, 96);
            short8 AC0 = LDA_(OW_C0, 0, 0, 32);
            short8 AC1 = LDA_(OW_C1, 0, 0, 32);
            float wa = (kq & 1) ? w2 : w0;
            float wb = (kq & 1) ? w6 : w4;
            float wsel0 = (kq & 2) ? wb : wa;
            float wc = (kq & 1) ? w3 : w1;
            float wd = (kq & 1) ? w7 : w5;
            float wsel1 = (kq & 2) ? wd : wc;
            TAIL(p00, p01, wsel0, 2 * kq + 0)
            TAIL(p10, p11, wsel1, 2 * kq + 1)
        }
    }
    if (l < 16) {
        out[p * 3 + 0] = rgbA0;
        out[p * 3 + 1] = rgbA1;
        out[p * 3 + 2] = rgbA2;
    }
}

extern "C" void kernel_launch(void* const* d_in, const int* in_sizes, int n_in,
                              void* d_out, int out_size, void* d_ws, size_t ws_size,
                              hipStream_t stream) {
    const float* coor  = (const float*)d_in[0];
    const float* view  = (const float*)d_in[1];
    const float* slots = (const float*)d_in[2];
    const float* dens  = (const float*)d_in[3];
    const float* shf   = (const float*)d_in[4];
    const float* Wb0 = (const float*)d_in[5];  const float* bb0 = (const float*)d_in[6];
    const float* Wb1 = (const float*)d_in[7];  const float* bb1 = (const float*)d_in[8];
    const float* Wb2 = (const float*)d_in[9];  const float* bb2 = (const float*)d_in[10];
    const float* Wa0 = (const float*)d_in[11]; const float* ba0 = (const float*)d_in[12];
    const float* Wa1 = (const float*)d_in[13]; const float* ba1 = (const float*)d_in[14];
    const float* Wa2 = (const float*)d_in[15]; const float* ba2 = (const float*)d_in[16];
    const float* Wl  = (const float*)d_in[17]; const float* bl  = (const float*)d_in[18];
    const float* Wv  = (const float*)d_in[19]; const float* bv  = (const float*)d_in[20];
    const float* Wc0 = (const float*)d_in[21]; const float* bc0 = (const float*)d_in[22];
    const float* Wc1 = (const float*)d_in[23]; const float* bc1 = (const float*)d_in[24];
    const int*   ray = (const int*)d_in[25];
    float* out = (float*)d_out;

    prep_kernel<<<dim3(1), dim3(256), 0, stream>>>(
        slots, Wb0, bb0, Wb1, bb1, Wb2, bb2,
        Wa0, ba0, Wa1, ba1, Wa2, ba2,
        Wl, bl, Wv, bv, Wc0, bc0, Wc1, bc1, (char*)d_ws);

    decoder_kernel<<<dim3(PP / 64), dim3(256), 0, stream>>>(
        coor, view, dens, shf, ray, (const char*)d_ws, out);
}